// Round 5
// baseline (289.715 us; speedup 1.0000x reference)
//
#include <hip/hip_runtime.h>
#include <math.h>

// DTW 2048x2048, single workgroup of 256 threads (4 waves).
// Thread = lane ln of wave wv owns 8 columns; row-blocks of BR=8 rows.
// In-wave left-boundary exchange via __shfl_up (lag 1, no barrier);
// across the 3 wave boundaries a ring mailbox in LDS with one barrier per
// KK=8 iterations (DELTA = KK+64 inter-wave skew -> provably race-free).
// Cell loops are plain nested r/k loops (NO conditionals) so the compiler
// fully unrolls and keeps all DP state in VGPRs (R3/R4 regression was
// scratch spill from a conditional anti-diagonal loop: VGPR_Count 20/28).
// Exchange + next-src prefetch issued at the BOTTOM of iteration n,
// consumed at n+1 (latency overlapped with loop back-edge).

#define MM 2048
#define NN 2048
#define BR 8
#define BC 8
#define NT 256
#define NB (MM / BR)                 // 256 row-blocks
#define KK 8                         // barrier period (iterations)
#define DELTA (KK + 64)              // 72: skew between adjacent waves
#define MAXSKEW (63 + 3 * DELTA)     // 279
#define NITER (NB + MAXSKEW)         // 535
#define NSP ((NITER + KK - 1) / KK)  // 67 superphases
#define RING (2 * KK)                // 16 mailbox slots per boundary
#define INFV 1e30f

__launch_bounds__(NT, 1)
__global__ void dtw_kernel(const float* __restrict__ src,
                           const float* __restrict__ tgt,
                           float* __restrict__ out)
{
    __shared__ float  s_srcT[BR * NB];   // transposed: [r][bi], stride-1 lane reads
    __shared__ float4 mbox[3][RING][2];  // wave-boundary right-column ring

    const int tid  = threadIdx.x;
    const int wv   = tid >> 6;
    const int ln   = tid & 63;
    const int skew = ln + wv * DELTA;

    for (int i = tid; i < MM; i += NT)
        s_srcT[(i & 7) * NB + (i >> 3)] = src[i];

    float tg[BC];
    #pragma unroll
    for (int k = 0; k < BC; ++k) tg[k] = tgt[tid * BC + k];

    // cur[] = bottom row of previous row-block (row-0 boundary = INF)
    float cur[BC];
    #pragma unroll
    for (int k = 0; k < BC; ++k) cur[k] = INFV;

    // corner = D[bi*BR][j0-1]; D[0][0]=0 for tid 0, else INF
    float corner = (tid == 0) ? 0.0f : INFV;

    // rcp = right column of my previous block (INFV while inactive)
    float rcp[BR];
    #pragma unroll
    for (int r = 0; r < BR; ++r) rcp[r] = INFV;

    __syncthreads();

    // ---- pipelined inputs for iteration 0 ----
    float lc[BR], psrow[BR];
    {
        #pragma unroll
        for (int r = 0; r < BR; ++r) lc[r] = INFV;
        int bin = 0 - skew; if (bin < 0) bin = 0;
        #pragma unroll
        for (int r = 0; r < BR; ++r) psrow[r] = s_srcT[r * NB + bin];
    }

    for (int sp = 0; sp < NSP; ++sp) {
        #pragma unroll 1
        for (int it = 0; it < KK; ++it) {
            const int n  = sp * KK + it;
            const int bi = n - skew;

            if (0 <= bi && bi < NB) {
                float rc[BR];
                float dl = corner;                  // D[i-1][j0-1] for row 0
                #pragma unroll
                for (int r = 0; r < BR; ++r) {
                    float l   = lc[r];              // D[i][j0-1]
                    float sv  = psrow[r];
                    float dgk = dl;                 // diag for k=0
                    #pragma unroll
                    for (int k = 0; k < BC; ++k) {
                        float up = cur[k];
                        float m  = fminf(fminf(up, l), dgk);
                        float d  = sv - tg[k];
                        float v  = fmaf(d, d, m);
                        dgk = up; cur[k] = v; l = v;
                    }
                    rc[r] = l;
                    dl = lc[r];
                }
                corner = lc[BR - 1];
                #pragma unroll
                for (int r = 0; r < BR; ++r) rcp[r] = rc[r];
                if (ln == 63 && wv < 3) {
                    const int sl = n & (RING - 1);
                    mbox[wv][sl][0] = make_float4(rcp[0], rcp[1], rcp[2], rcp[3]);
                    mbox[wv][sl][1] = make_float4(rcp[4], rcp[5], rcp[6], rcp[7]);
                }
            }

            // ---- bottom: prepare iteration n+1 (unconditional) ----
            {
                int bin = n + 1 - skew;
                if (bin < 0) bin = 0;
                if (bin > NB - 1) bin = NB - 1;
                #pragma unroll
                for (int r = 0; r < BR; ++r) psrow[r] = s_srcT[r * NB + bin];

                float sh[BR];
                #pragma unroll
                for (int r = 0; r < BR; ++r) sh[r] = __shfl_up(rcp[r], 1);

                float mb[BR];
                if (wv > 0) {                        // wave-uniform branch
                    const int sl = (n - KK) & (RING - 1);
                    float4 m0 = mbox[wv - 1][sl][0]; // broadcast read
                    float4 m1 = mbox[wv - 1][sl][1];
                    mb[0] = m0.x; mb[1] = m0.y; mb[2] = m0.z; mb[3] = m0.w;
                    mb[4] = m1.x; mb[5] = m1.y; mb[6] = m1.z; mb[7] = m1.w;
                } else {
                    #pragma unroll
                    for (int r = 0; r < BR; ++r) mb[r] = INFV;
                }
                #pragma unroll
                for (int r = 0; r < BR; ++r)
                    lc[r] = (ln == 0) ? mb[r] : sh[r];
            }
        }
        __syncthreads();
    }

    // tid 255 computed block (NB-1, strip 255) at n = 534; cur[7] = D[2048][2048]
    if (tid == NT - 1) out[0] = sqrtf(cur[BC - 1]);
}

extern "C" void kernel_launch(void* const* d_in, const int* in_sizes, int n_in,
                              void* d_out, int out_size, void* d_ws, size_t ws_size,
                              hipStream_t stream)
{
    (void)in_sizes; (void)n_in; (void)out_size; (void)d_ws; (void)ws_size;
    const float* source = (const float*)d_in[0];
    const float* target = (const float*)d_in[1];
    float* out = (float*)d_out;
    dtw_kernel<<<1, NT, 0, stream>>>(source, target, out);
}

// Round 6
// 289.081 us; speedup vs baseline: 1.0022x; 1.0022x over previous
//
#include <hip/hip_runtime.h>
#include <math.h>

// DTW 2048x2048, single workgroup of 256 threads (4 waves).
// Identical schedule to R5 (BR=8, KK=8 ring mailbox, bottom-pipelined
// exchange/prefetch) but ALL per-thread DP state is named scalars --
// R3/R4/R5 kept arrays in scratch (VGPR_Count 20/28 << 41 live floats),
// paying spill latency every cell. Scalars cannot be demoted to scratch.

#define MM 2048
#define NN 2048
#define BR 8
#define BC 8
#define NT 256
#define NB (MM / BR)                 // 256 row-blocks
#define KK 8                         // barrier period (iterations)
#define DELTA (KK + 64)              // 72: skew between adjacent waves
#define MAXSKEW (63 + 3 * DELTA)     // 279
#define NITER (NB + MAXSKEW)         // 535
#define NSP ((NITER + KK - 1) / KK)  // 67 superphases
#define RING (2 * KK)                // 16 mailbox slots per boundary
#define INFV 1e30f

__launch_bounds__(NT, 1)
__global__ void dtw_kernel(const float* __restrict__ src,
                           const float* __restrict__ tgt,
                           float* __restrict__ out)
{
    __shared__ float  s_srcT[BR * NB];   // transposed: [r][bi], stride-1 lane reads
    __shared__ float4 mbox[3][RING][2];  // wave-boundary right-column ring

    const int tid  = threadIdx.x;
    const int wv   = tid >> 6;
    const int ln   = tid & 63;
    const int skew = ln + wv * DELTA;

    for (int i = tid; i < MM; i += NT)
        s_srcT[(i & 7) * NB + (i >> 3)] = src[i];

    const float* tgp = tgt + tid * BC;
    float tg0 = tgp[0], tg1 = tgp[1], tg2 = tgp[2], tg3 = tgp[3],
          tg4 = tgp[4], tg5 = tgp[5], tg6 = tgp[6], tg7 = tgp[7];

    // bottom row of previous row-block (row-0 boundary = INF)
    float cur0 = INFV, cur1 = INFV, cur2 = INFV, cur3 = INFV,
          cur4 = INFV, cur5 = INFV, cur6 = INFV, cur7 = INFV;

    // corner = D[bi*BR][j0-1]; D[0][0]=0 for tid 0, else INF
    float corner = (tid == 0) ? 0.0f : INFV;

    // right column of my previous block (INFV while inactive)
    float rcp0 = INFV, rcp1 = INFV, rcp2 = INFV, rcp3 = INFV,
          rcp4 = INFV, rcp5 = INFV, rcp6 = INFV, rcp7 = INFV;

    // pipelined inputs for iteration 0
    float lc0 = INFV, lc1 = INFV, lc2 = INFV, lc3 = INFV,
          lc4 = INFV, lc5 = INFV, lc6 = INFV, lc7 = INFV;
    float ps0, ps1, ps2, ps3, ps4, ps5, ps6, ps7;

    __syncthreads();

    {
        int bin = 0 - skew; if (bin < 0) bin = 0;
        const float* sb = s_srcT + bin;
        ps0 = sb[0 * NB]; ps1 = sb[1 * NB]; ps2 = sb[2 * NB]; ps3 = sb[3 * NB];
        ps4 = sb[4 * NB]; ps5 = sb[5 * NB]; ps6 = sb[6 * NB]; ps7 = sb[7 * NB];
    }

#define CELL(CUR, TG) { float up = (CUR); float m = fminf(fminf(up, l), dgk); \
                        float d = sv - (TG); float v = fmaf(d, d, m);          \
                        dgk = up; (CUR) = v; l = v; }
#define ROW(PS, LC, DG, RC) { float l = (LC); float sv = (PS); float dgk = (DG); \
        CELL(cur0, tg0) CELL(cur1, tg1) CELL(cur2, tg2) CELL(cur3, tg3)           \
        CELL(cur4, tg4) CELL(cur5, tg5) CELL(cur6, tg6) CELL(cur7, tg7)           \
        (RC) = l; }

    for (int sp = 0; sp < NSP; ++sp) {
        #pragma unroll 1
        for (int it = 0; it < KK; ++it) {
            const int n  = sp * KK + it;
            const int bi = n - skew;

            if (0 <= bi && bi < NB) {
                float rc0, rc1, rc2, rc3, rc4, rc5, rc6, rc7;
                ROW(ps0, lc0, corner, rc0)
                ROW(ps1, lc1, lc0,    rc1)
                ROW(ps2, lc2, lc1,    rc2)
                ROW(ps3, lc3, lc2,    rc3)
                ROW(ps4, lc4, lc3,    rc4)
                ROW(ps5, lc5, lc4,    rc5)
                ROW(ps6, lc6, lc5,    rc6)
                ROW(ps7, lc7, lc6,    rc7)
                corner = lc7;
                rcp0 = rc0; rcp1 = rc1; rcp2 = rc2; rcp3 = rc3;
                rcp4 = rc4; rcp5 = rc5; rcp6 = rc6; rcp7 = rc7;
                if (ln == 63 && wv < 3) {
                    const int sl = n & (RING - 1);
                    mbox[wv][sl][0] = make_float4(rcp0, rcp1, rcp2, rcp3);
                    mbox[wv][sl][1] = make_float4(rcp4, rcp5, rcp6, rcp7);
                }
            }

            // ---- bottom: prepare iteration n+1 (unconditional) ----
            {
                int bin = n + 1 - skew;
                if (bin < 0) bin = 0;
                if (bin > NB - 1) bin = NB - 1;
                const float* sb = s_srcT + bin;
                ps0 = sb[0 * NB]; ps1 = sb[1 * NB]; ps2 = sb[2 * NB]; ps3 = sb[3 * NB];
                ps4 = sb[4 * NB]; ps5 = sb[5 * NB]; ps6 = sb[6 * NB]; ps7 = sb[7 * NB];

                float sh0 = __shfl_up(rcp0, 1), sh1 = __shfl_up(rcp1, 1);
                float sh2 = __shfl_up(rcp2, 1), sh3 = __shfl_up(rcp3, 1);
                float sh4 = __shfl_up(rcp4, 1), sh5 = __shfl_up(rcp5, 1);
                float sh6 = __shfl_up(rcp6, 1), sh7 = __shfl_up(rcp7, 1);

                float mb0, mb1, mb2, mb3, mb4, mb5, mb6, mb7;
                if (wv > 0) {                      // wave-uniform branch
                    const int sl = (n - KK) & (RING - 1);
                    float4 m0 = mbox[wv - 1][sl][0];
                    float4 m1 = mbox[wv - 1][sl][1];
                    mb0 = m0.x; mb1 = m0.y; mb2 = m0.z; mb3 = m0.w;
                    mb4 = m1.x; mb5 = m1.y; mb6 = m1.z; mb7 = m1.w;
                } else {
                    mb0 = mb1 = mb2 = mb3 = mb4 = mb5 = mb6 = mb7 = INFV;
                }
                const bool z = (ln == 0);
                lc0 = z ? mb0 : sh0; lc1 = z ? mb1 : sh1;
                lc2 = z ? mb2 : sh2; lc3 = z ? mb3 : sh3;
                lc4 = z ? mb4 : sh4; lc5 = z ? mb5 : sh5;
                lc6 = z ? mb6 : sh6; lc7 = z ? mb7 : sh7;
            }
        }
        __syncthreads();
    }
#undef ROW
#undef CELL

    // tid 255 computed block (NB-1, strip 255) at n = NITER-1; cur7 = D[2048][2048]
    if (tid == NT - 1) out[0] = sqrtf(cur7);
}

extern "C" void kernel_launch(void* const* d_in, const int* in_sizes, int n_in,
                              void* d_out, int out_size, void* d_ws, size_t ws_size,
                              hipStream_t stream)
{
    (void)in_sizes; (void)n_in; (void)out_size; (void)d_ws; (void)ws_size;
    const float* source = (const float*)d_in[0];
    const float* target = (const float*)d_in[1];
    float* out = (float*)d_out;
    dtw_kernel<<<1, NT, 0, stream>>>(source, target, out);
}

// Round 7
// 266.143 us; speedup vs baseline: 1.0886x; 1.0862x over previous
//
#include <hip/hip_runtime.h>
#include <math.h>

// DTW 2048x2048, single workgroup of 256 threads (4 waves).
// Lane owns 8 columns; row-blocks of BR=8 rows; 535 iterations.
// R7 changes vs R6 (same schedule, same mailbox timing):
//  - in-wave left-boundary exchange via DPP wave_shr1 (VALU) instead of
//    ds_bpermute shfl -> no LDS-pipe op, no lgkmcnt drain on the chain
//  - src row reads double-buffered two iterations ahead (psA/psB named
//    scalars, manual 2x unroll) -> ds_read latency fully slack-covered
//  - mailbox LDS read issued at bottom of iter n, SELECTED at top of
//    iter n+1 -> one full iteration of latency slack

#define MM 2048
#define NN 2048
#define BR 8
#define BC 8
#define NT 256
#define NB (MM / BR)                 // 256 row-blocks
#define KK 8                         // barrier period (iterations)
#define DELTA (KK + 64)              // 72: skew between adjacent waves
#define MAXSKEW (63 + 3 * DELTA)     // 279
#define NITER (NB + MAXSKEW)         // 535
#define NSP ((NITER + KK - 1) / KK)  // 67 superphases
#define RING (2 * KK)                // 16 mailbox slots per boundary
#define INFV 1e30f

__device__ __forceinline__ float wave_shr1(float x) {
    // full-wave shift right by one lane (lane i <- lane i-1); lane 0 keeps x
    int xi = __float_as_int(x);
    int r  = __builtin_amdgcn_update_dpp(xi, xi, 0x138 /*WAVE_SHR1*/, 0xF, 0xF, false);
    return __int_as_float(r);
}

__launch_bounds__(NT, 1)
__global__ void dtw_kernel(const float* __restrict__ src,
                           const float* __restrict__ tgt,
                           float* __restrict__ out)
{
    __shared__ float  s_srcT[BR * NB];   // transposed: [r][bi], stride-1 lane reads
    __shared__ float4 mbox[3][RING][2];  // wave-boundary right-column ring

    const int tid  = threadIdx.x;
    const int wv   = tid >> 6;
    const int ln   = tid & 63;
    const int skew = ln + wv * DELTA;

    for (int i = tid; i < MM; i += NT)
        s_srcT[(i & 7) * NB + (i >> 3)] = src[i];

    const float* tgp = tgt + tid * BC;
    float tg0 = tgp[0], tg1 = tgp[1], tg2 = tgp[2], tg3 = tgp[3],
          tg4 = tgp[4], tg5 = tgp[5], tg6 = tgp[6], tg7 = tgp[7];

    float cur0 = INFV, cur1 = INFV, cur2 = INFV, cur3 = INFV,
          cur4 = INFV, cur5 = INFV, cur6 = INFV, cur7 = INFV;

    float corner = (tid == 0) ? 0.0f : INFV;

    float rcp0 = INFV, rcp1 = INFV, rcp2 = INFV, rcp3 = INFV,
          rcp4 = INFV, rcp5 = INFV, rcp6 = INFV, rcp7 = INFV;

    // exchange pipeline regs (feed the top-of-iteration select)
    float sh0 = INFV, sh1 = INFV, sh2 = INFV, sh3 = INFV,
          sh4 = INFV, sh5 = INFV, sh6 = INFV, sh7 = INFV;
    float mb0 = INFV, mb1 = INFV, mb2 = INFV, mb3 = INFV,
          mb4 = INFV, mb5 = INFV, mb6 = INFV, mb7 = INFV;

    float psA0, psA1, psA2, psA3, psA4, psA5, psA6, psA7;
    float psB0, psB1, psB2, psB3, psB4, psB5, psB6, psB7;

    __syncthreads();

    {   // src blocks for iterations 0 and 1 (clamped; inactive lanes read junk-safe)
        int b0 = 0 - skew; if (b0 < 0) b0 = 0;
        int b1 = 1 - skew; if (b1 < 0) b1 = 0;
        const float* sa = s_srcT + b0;
        const float* sb = s_srcT + b1;
        psA0 = sa[0*NB]; psA1 = sa[1*NB]; psA2 = sa[2*NB]; psA3 = sa[3*NB];
        psA4 = sa[4*NB]; psA5 = sa[5*NB]; psA6 = sa[6*NB]; psA7 = sa[7*NB];
        psB0 = sb[0*NB]; psB1 = sb[1*NB]; psB2 = sb[2*NB]; psB3 = sb[3*NB];
        psB4 = sb[4*NB]; psB5 = sb[5*NB]; psB6 = sb[6*NB]; psB7 = sb[7*NB];
    }

#define CELL(CUR, TG) { float up = (CUR); float m = fminf(fminf(up, l), dgk); \
                        float d = sv - (TG); float v = fmaf(d, d, m);          \
                        dgk = up; (CUR) = v; l = v; }
#define ROWX(SV, LCV, DGV, RC) { float l = (LCV); float sv = (SV); float dgk = (DGV); \
        CELL(cur0, tg0) CELL(cur1, tg1) CELL(cur2, tg2) CELL(cur3, tg3)               \
        CELL(cur4, tg4) CELL(cur5, tg5) CELL(cur6, tg6) CELL(cur7, tg7)               \
        (RC) = l; }

#define ITER(N_, P0,P1,P2,P3,P4,P5,P6,P7)                                             \
    {                                                                                 \
        const int n_ = (N_);                                                          \
        const bool z_ = (ln == 0);                                                    \
        float lc0 = z_ ? mb0 : sh0, lc1 = z_ ? mb1 : sh1;                             \
        float lc2 = z_ ? mb2 : sh2, lc3 = z_ ? mb3 : sh3;                             \
        float lc4 = z_ ? mb4 : sh4, lc5 = z_ ? mb5 : sh5;                             \
        float lc6 = z_ ? mb6 : sh6, lc7 = z_ ? mb7 : sh7;                             \
        const int bi_ = n_ - skew;                                                    \
        if (0 <= bi_ && bi_ < NB) {                                                   \
            float rc0, rc1, rc2, rc3, rc4, rc5, rc6, rc7;                             \
            ROWX(P0, lc0, corner, rc0)                                                \
            ROWX(P1, lc1, lc0,    rc1)                                                \
            ROWX(P2, lc2, lc1,    rc2)                                                \
            ROWX(P3, lc3, lc2,    rc3)                                                \
            ROWX(P4, lc4, lc3,    rc4)                                                \
            ROWX(P5, lc5, lc4,    rc5)                                                \
            ROWX(P6, lc6, lc5,    rc6)                                                \
            ROWX(P7, lc7, lc6,    rc7)                                                \
            corner = lc7;                                                             \
            rcp0 = rc0; rcp1 = rc1; rcp2 = rc2; rcp3 = rc3;                           \
            rcp4 = rc4; rcp5 = rc5; rcp6 = rc6; rcp7 = rc7;                           \
            if (ln == 63 && wv < 3) {                                                 \
                const int sl_ = n_ & (RING - 1);                                      \
                mbox[wv][sl_][0] = make_float4(rcp0, rcp1, rcp2, rcp3);               \
                mbox[wv][sl_][1] = make_float4(rcp4, rcp5, rcp6, rcp7);               \
            }                                                                         \
        }                                                                             \
        {   /* prefetch src for iteration n_+2 into the set just consumed */          \
            int bin_ = n_ + 2 - skew;                                                 \
            if (bin_ < 0) bin_ = 0;                                                   \
            if (bin_ > NB - 1) bin_ = NB - 1;                                         \
            const float* sp_ = s_srcT + bin_;                                         \
            P0 = sp_[0*NB]; P1 = sp_[1*NB]; P2 = sp_[2*NB]; P3 = sp_[3*NB];           \
            P4 = sp_[4*NB]; P5 = sp_[5*NB]; P6 = sp_[6*NB]; P7 = sp_[7*NB];           \
        }                                                                             \
        sh0 = wave_shr1(rcp0); sh1 = wave_shr1(rcp1);                                 \
        sh2 = wave_shr1(rcp2); sh3 = wave_shr1(rcp3);                                 \
        sh4 = wave_shr1(rcp4); sh5 = wave_shr1(rcp5);                                 \
        sh6 = wave_shr1(rcp6); sh7 = wave_shr1(rcp7);                                 \
        if (wv > 0) {            /* wave-uniform broadcast read, used next iter */    \
            const int sl_ = (n_ - KK) & (RING - 1);                                   \
            float4 m0_ = mbox[wv - 1][sl_][0];                                        \
            float4 m1_ = mbox[wv - 1][sl_][1];                                        \
            mb0 = m0_.x; mb1 = m0_.y; mb2 = m0_.z; mb3 = m0_.w;                       \
            mb4 = m1_.x; mb5 = m1_.y; mb6 = m1_.z; mb7 = m1_.w;                       \
        }                                                                             \
    }

    for (int sp = 0; sp < NSP; ++sp) {
        const int n0 = sp * KK;
        #pragma unroll 1
        for (int it = 0; it < KK; it += 2) {
            ITER(n0 + it,     psA0, psA1, psA2, psA3, psA4, psA5, psA6, psA7)
            ITER(n0 + it + 1, psB0, psB1, psB2, psB3, psB4, psB5, psB6, psB7)
        }
        __syncthreads();
    }
#undef ITER
#undef ROWX
#undef CELL

    // tid 255 computed block (NB-1, strip 255) at n = 534; cur7 = D[2048][2048]
    if (tid == NT - 1) out[0] = sqrtf(cur7);
}

extern "C" void kernel_launch(void* const* d_in, const int* in_sizes, int n_in,
                              void* d_out, int out_size, void* d_ws, size_t ws_size,
                              hipStream_t stream)
{
    (void)in_sizes; (void)n_in; (void)out_size; (void)d_ws; (void)ws_size;
    const float* source = (const float*)d_in[0];
    const float* target = (const float*)d_in[1];
    float* out = (float*)d_out;
    dtw_kernel<<<1, NT, 0, stream>>>(source, target, out);
}